// Round 10
// baseline (345.929 us; speedup 1.0000x reference)
//
#include <hip/hip_runtime.h>

// ---------------------------------------------------------------------------
// HFLongFormerSelfAttentionBlock — MI355X implementation (round 16)
//
// I/O fp32; internal bf16 MFMA, fp32 accumulation/epilogues.
// Round-16:
//  * attn: q-chunk 128 -> 64. Old grid 512 = 2 blocks/CU (grid-capped, the
//    same disease as MLP2 in r9); new grid 1024, LDS 36.4 KB -> 4 blocks/CU,
//    per-block state halved (VGPR ~100 fits 4 waves/SIMD). T14 async staging
//    kept. Boundary K-tiles (jb not 128-aligned anymore) handled by clamping
//    load rows to [0,2047] and masking jcol outside [0,2048) to NEGF
//    (garbage K/V provably nulled: score->NEGF -> P=0).
//  * MLP2: back to r6 gemm64_db (64^2, 4 blk/CU, dbuf+vmcnt(4)) — measured
//    59us vs 62us for 128x64@2blk/CU; tile space is grid-constrained.
// ---------------------------------------------------------------------------

using bf16x8 = __attribute__((ext_vector_type(8))) short;
using bf16x4 = __attribute__((ext_vector_type(4))) short;
using f32x4  = __attribute__((ext_vector_type(4))) float;

__device__ __forceinline__ float b2f(short s) {
    return __uint_as_float(((unsigned int)(unsigned short)s) << 16);
}
__device__ __forceinline__ short f2b(float f) {
    unsigned int u = __float_as_uint(f);
    u += 0x7fffu + ((u >> 16) & 1u);   // round-to-nearest-even
    return (short)(u >> 16);
}
__device__ __forceinline__ f32x4 mfma16(bf16x8 a, bf16x8 b, f32x4 c) {
    return __builtin_amdgcn_mfma_f32_16x16x32_bf16(a, b, c, 0, 0, 0);
}
// args are always <= 0 here (online-softmax differences); __expf -> v_exp_f32
__device__ __forceinline__ float safe_exp(float x) {
    return __expf((x <= 0.f) ? x : 0.f);
}
// gelu(v) = 0.5 v (1 + erf(v/sqrt2)); erf via A&S 7.1.25 (|err| <= 2.5e-5,
// branch-free: rcp + exp + 5 fma). 100x below bf16 output quantization.
__device__ __forceinline__ float fast_gelu(float v) {
    float z  = fabsf(v) * 0.70710678118f;
    float t  = __builtin_amdgcn_rcpf(fmaf(0.47047f, z, 1.f));
    float e  = __expf(-z * z);
    float p  = t * fmaf(t, fmaf(t, 0.7478556f, -0.0958798f), 0.3480242f);
    float er = fmaf(-p, e, 1.f);                  // erf(|z|)
    er = (v < 0.f) ? -er : er;
    return 0.5f * v * (1.f + er);
}
// async global->LDS, 16 B per lane; LDS dest = wave-uniform base + lane*16
__device__ __forceinline__ void load_lds16(const short* g, short* l) {
    __builtin_amdgcn_global_load_lds((const __attribute__((address_space(1))) void*)g,
                                     (__attribute__((address_space(3))) void*)l, 16, 0, 0);
}
// raw barrier: LDS writes made visible, but in-flight GLOBAL loads are NOT
// drained (unlike __syncthreads' s_waitcnt vmcnt(0)) — the T14 enabler.
__device__ __forceinline__ void barrier_lds_only() {
    asm volatile("s_waitcnt lgkmcnt(0)" ::: "memory");
    __builtin_amdgcn_s_barrier();
    asm volatile("" ::: "memory");
}
#define NEGF (-3.0e38f)

// ---------------------------------------------------------------------------
// fp32 -> bf16 elementwise convert (n multiple of 1024). grid n/1024, 256 thr
// ---------------------------------------------------------------------------
__global__ void cvt_f32_bf16(const float* __restrict__ in, short* __restrict__ out, int n) {
    int i = (blockIdx.x * 256 + threadIdx.x) * 4;
    f32x4 v = *(const f32x4*)(in + i);
    bf16x4 o;
#pragma unroll
    for (int j = 0; j < 4; ++j) o[j] = f2b(v[j]);
    *(bf16x4*)(out + i) = o;
}

// ---------------------------------------------------------------------------
// fp32 in, bf16 transposed out: out[c][r] = in[r][c], in is R x C.
// grid (C/32, R/32), block (32,8)
// ---------------------------------------------------------------------------
__global__ void cvt_transpose(const float* __restrict__ in, short* __restrict__ out,
                              int R, int C) {
    __shared__ short tile[32][33];
    int bx = blockIdx.x * 32, by = blockIdx.y * 32;
    int tx = threadIdx.x, ty = threadIdx.y;
    for (int i = ty; i < 32; i += 8)
        tile[i][tx] = f2b(in[(size_t)(by + i) * C + bx + tx]);
    __syncthreads();
    for (int i = ty; i < 32; i += 8)
        out[(size_t)(bx + i) * R + by + tx] = tile[tx][i];
}

// wq/wk/wv (each 1024x1024 fp32) -> WQKVT (3072x1024 bf16, = [wq^T;wk^T;wv^T])
__global__ void cvt_transpose_qkv(const float* __restrict__ wq, const float* __restrict__ wk,
                                  const float* __restrict__ wv, short* __restrict__ out) {
    __shared__ short tile[32][33];
    const float* in = (blockIdx.z == 0) ? wq : (blockIdx.z == 1) ? wk : wv;
    short* dst = out + (size_t)blockIdx.z * 1024 * 1024;
    int bx = blockIdx.x * 32, by = blockIdx.y * 32;
    int tx = threadIdx.x, ty = threadIdx.y;
    for (int i = ty; i < 32; i += 8)
        tile[i][tx] = f2b(in[(size_t)(by + i) * 1024 + bx + tx]);
    __syncthreads();
    for (int i = ty; i < 32; i += 8)
        dst[(size_t)(bx + i) * 1024 + by + tx] = tile[tx][i];
}

// ---------------------------------------------------------------------------
// GEMM 128x128, BK=64, XOR-swizzled LDS k-chunks. NATURAL block order.
// mode 0: QKV — bias by col segment, Q scaled, V staged+transposed -> Vt
// mode 1: C = bf16(gelu(acc + bias0[col]))
// Epilogue always stages the tile in LDS, then coalesced 16-B stores.
// ---------------------------------------------------------------------------
__global__ __launch_bounds__(256, 4) void gemm_bt(
    const short* __restrict__ A, const short* __restrict__ Bt,
    const float* __restrict__ bias0, const float* __restrict__ bias1,
    const float* __restrict__ bias2,
    short* __restrict__ C, short* __restrict__ Vt,
    int M, int N, int K, float scale, int mode)
{
    __shared__ short sh[128 * 136];   // 34.8 KB; main loop uses first 16K shorts
    short* As = sh;
    short* Bs = sh + 8192;
    int m0 = blockIdx.x * 128, n0 = blockIdx.y * 128;
    int t = threadIdx.x;
    int wave = t >> 6, lane = t & 63, quad = lane >> 4, l16 = lane & 15;
    int wr = (wave >> 1) * 64, wc = (wave & 1) * 64;

    // staging pointers: 4 chunks per wave per buffer
    const short* ap[4]; const short* bp[4]; short* la[4]; short* lb[4];
    int gk = (((lane & 7) ^ (lane >> 3)) * 8);
#pragma unroll
    for (int l = 0; l < 4; ++l) {
        int c = wave * 4 + l;
        int row = c * 8 + (lane >> 3);
        ap[l] = A  + (size_t)(m0 + row) * K + gk;
        bp[l] = Bt + (size_t)(n0 + row) * K + gk;
        la[l] = As + c * 512;
        lb[l] = Bs + c * 512;
    }
    int sw = l16 & 7;   // frag-read swizzle key

    f32x4 acc[4][4] = {};
    for (int k0 = 0; k0 < K; k0 += 64) {
#pragma unroll
        for (int l = 0; l < 4; ++l) { load_lds16(ap[l] + k0, la[l]); load_lds16(bp[l] + k0, lb[l]); }
        __syncthreads();
#pragma unroll
        for (int ks = 0; ks < 2; ++ks) {
            int slot = ((ks * 4 + quad) ^ sw) * 8;
            bf16x8 af[4], bfr[4];
#pragma unroll
            for (int i = 0; i < 4; ++i)
                af[i] = *(bf16x8*)(As + (wr + i * 16 + l16) * 64 + slot);
#pragma unroll
            for (int j = 0; j < 4; ++j)
                bfr[j] = *(bf16x8*)(Bs + (wc + j * 16 + l16) * 64 + slot);
#pragma unroll
            for (int i = 0; i < 4; ++i)
#pragma unroll
                for (int j = 0; j < 4; ++j)
                    acc[i][j] = mfma16(af[i], bfr[j], acc[i][j]);
        }
        __syncthreads();
    }
    // after final barrier, all LDS reads are done -> sh reusable for staging

    int seg0 = n0 >> 10;   // tiles are 128-aligned: never straddle a segment
    if (mode == 1 || seg0 < 2) {
        // ---- stage bf16 tile in LDS: sh[row*136 + col], row/col in [0,128)
        if (mode == 1) {
#pragma unroll
            for (int j = 0; j < 4; ++j) {
                int col = n0 + wc + j * 16 + l16;
                float bs = bias0[col];
#pragma unroll
                for (int i = 0; i < 4; ++i)
#pragma unroll
                    for (int r = 0; r < 4; ++r) {
                        float v = fast_gelu(acc[i][j][r] + bs);
                        sh[(wr + i * 16 + quad * 4 + r) * 136 + wc + j * 16 + l16] = f2b(v);
                    }
            }
        } else {
            float sc = (seg0 == 0) ? scale : 1.0f;
            const float* bpt = (seg0 == 0) ? bias0 : bias1;
#pragma unroll
            for (int j = 0; j < 4; ++j) {
                int col = n0 + wc + j * 16 + l16;
                float bs = bpt[col & 1023];
#pragma unroll
                for (int i = 0; i < 4; ++i)
#pragma unroll
                    for (int r = 0; r < 4; ++r)
                        sh[(wr + i * 16 + quad * 4 + r) * 136 + wc + j * 16 + l16] =
                            f2b((acc[i][j][r] + bs) * sc);
            }
        }
        __syncthreads();
        // ---- coalesced write-out: 2 threads per row, 8 x 16 B each
        int row = t >> 1, half = t & 1;
        const short* src = sh + row * 136 + half * 64;
        short* dst = C + (size_t)(m0 + row) * N + n0 + half * 64;
#pragma unroll
        for (int cgk = 0; cgk < 8; ++cgk)
            *(bf16x8*)(dst + cgk * 8) = *(const bf16x8*)(src + cgk * 8);
    } else {
        // ---- V part: stage TRANSPOSED in LDS (sh[c*136 + row]), then write
        //      Vt (b, h, d, s) with 16-B chunks coalesced along s.
#pragma unroll
        for (int j = 0; j < 4; ++j) {
            int cl = wc + j * 16 + l16;                 // local col in [0,128)
            float bs = bias2[(n0 & 1023) + cl];
#pragma unroll
            for (int i = 0; i < 4; ++i)
#pragma unroll
                for (int r = 0; r < 4; ++r)
                    sh[cl * 136 + wr + i * 16 + quad * 4 + r] = f2b(acc[i][j][r] + bs);
        }
        __syncthreads();
        int h0 = (n0 & 1023) >> 6;                      // first head of tile
        int bb = m0 >> 11, s0 = m0 & 2047;
        int sc = t & 15;                                // s-chunk within tile
#pragma unroll
        for (int cgk = 0; cgk < 8; ++cgk) {
            int cl = (t >> 4) + cgk * 16;               // local col
            int h = h0 + (cl >> 6), d = cl & 63;
            *(bf16x8*)(Vt + (((size_t)(bb * 16 + h)) * 64 + d) * 2048 + s0 + sc * 8) =
                *(const bf16x8*)(sh + cl * 136 + sc * 8);
        }
    }
}

// ---------------------------------------------------------------------------
// MLP2 GEMM: 64x64, BK=64, XOR swizzle, double-buffered with counted vmcnt(4).
// NATURAL block order (A partitioned m%8 across XCD L2s). 4 blocks/CU —
// measured-best config for this grid-constrained shape (r6: 59us).
// Cf = A@B + bias + resf (fp32 out). grid (M/64, N/64), 256 thr.
// ---------------------------------------------------------------------------
__global__ __launch_bounds__(256, 4) void gemm64_db(
    const short* __restrict__ A, const short* __restrict__ Bt,
    const float* __restrict__ bias, const float* __restrict__ resf,
    float* __restrict__ Cf, int M, int N, int K)
{
    __shared__ short As[2][64 * 64];
    __shared__ short Bs[2][64 * 64];
    int m0 = blockIdx.x * 64, n0 = blockIdx.y * 64;
    int t = threadIdx.x;
    int wave = t >> 6, lane = t & 63, quad = lane >> 4, l16 = lane & 15;
    int wr = (wave >> 1) * 32, wc = (wave & 1) * 32;

    const short* ap[2]; const short* bp[2]; int lo[2];
    int gk = (((lane & 7) ^ (lane >> 3)) * 8);
#pragma unroll
    for (int l = 0; l < 2; ++l) {
        int c = wave * 2 + l;
        int row = c * 8 + (lane >> 3);
        ap[l] = A  + (size_t)(m0 + row) * K + gk;
        bp[l] = Bt + (size_t)(n0 + row) * K + gk;
        lo[l] = c * 512;
    }
    int sw = l16 & 7;

    const int nt = K >> 6;
#pragma unroll
    for (int l = 0; l < 2; ++l) { load_lds16(ap[l], &As[0][lo[l]]); load_lds16(bp[l], &Bs[0][lo[l]]); }

    f32x4 acc[2][2] = {};
    for (int ti = 0; ti < nt; ++ti) {
        int cur = ti & 1;
        if (ti + 1 < nt) {
            int k0 = (ti + 1) << 6;
#pragma unroll
            for (int l = 0; l < 2; ++l) {
                load_lds16(ap[l] + k0, &As[cur ^ 1][lo[l]]);
                load_lds16(bp[l] + k0, &Bs[cur ^ 1][lo[l]]);
            }
            asm volatile("s_waitcnt vmcnt(4)" ::: "memory");  // wait cur's loads only
        } else {
            asm volatile("s_waitcnt vmcnt(0)" ::: "memory");
        }
        __builtin_amdgcn_s_barrier();
        asm volatile("" ::: "memory");

        const short* as = &As[cur][0];
        const short* bs = &Bs[cur][0];
#pragma unroll
        for (int ks = 0; ks < 2; ++ks) {
            int slot = ((ks * 4 + quad) ^ sw) * 8;
            bf16x8 af[2], bfr[2];
#pragma unroll
            for (int i = 0; i < 2; ++i)
                af[i] = *(bf16x8*)(as + (wr + i * 16 + l16) * 64 + slot);
#pragma unroll
            for (int j = 0; j < 2; ++j)
                bfr[j] = *(bf16x8*)(bs + (wc + j * 16 + l16) * 64 + slot);
#pragma unroll
            for (int i = 0; i < 2; ++i)
#pragma unroll
                for (int j = 0; j < 2; ++j)
                    acc[i][j] = mfma16(af[i], bfr[j], acc[i][j]);
        }
        asm volatile("" ::: "memory");
        __builtin_amdgcn_s_barrier();   // protect buf cur^1 before next stage
    }

#pragma unroll
    for (int j = 0; j < 2; ++j) {
        int col = n0 + wc + j * 16 + l16;
        float bs = bias[col];
#pragma unroll
        for (int i = 0; i < 2; ++i) {
#pragma unroll
            for (int r = 0; r < 4; ++r) {
                int row = m0 + wr + i * 16 + quad * 4 + r;
                Cf[(size_t)row * N + col] = acc[i][j][r] + bs + resf[(size_t)row * N + col];
            }
        }
    }
}

// ---------------------------------------------------------------------------
// Windowed attention with global column. Round-16: q-chunk 64 (grid 1024,
// 36.4 KB LDS -> 4 blocks/CU). T14 async staging. Boundary tiles: load rows
// clamped to [0,2047]; jcol outside [0,2048) masked to NEGF (=> P=0, so
// garbage K/V contributes nothing).
// smem: PsQ 17408 (Q 64x72 / P 64x136) | KV 18432 (K 128x72 / V 64x136)
//       | gkf 256 | gvf 256  = 36352 B
// ---------------------------------------------------------------------------
__global__ __launch_bounds__(256, 4) void attn_kernel(
    const short* __restrict__ QKV, const short* __restrict__ Vt,
    const int* __restrict__ mask,
    const float* __restrict__ bk, const float* __restrict__ bv,
    short* __restrict__ attn)
{
    extern __shared__ char smem[];
    short* PsQ = (short*)smem;
    short* KV  = (short*)(smem + 17408);
    float* gkf = (float*)(smem + 35840);
    float* gvf = (float*)(smem + 36096);

    int blk = blockIdx.x;
    int c = blk & 31, h = (blk >> 5) & 15, b = blk >> 9;
    int t = threadIdx.x;
    int wave = t >> 6, lane = t & 63, quad = lane >> 4, l16 = lane & 15;
    int q0 = c * 64;
    const int bs_off = b * 2048;
    const short* Q = QKV + h * 64;
    const short* K = QKV + 1024 + h * 64;
    const short* Vg = Vt + (size_t)(b * 16 + h) * 64 * 2048;

    // Q stage: 64 rows x 64 cols
#pragma unroll
    for (int l = 0; l < 2; ++l) {
        int idx = l * 256 + t;
        int p = idx >> 3, dc = (idx & 7) * 8;
        *(bf16x8*)(PsQ + p * 72 + dc) =
            *(const bf16x8*)(Q + ((size_t)(bs_off + q0 + p)) * 3072 + dc);
    }
    if (t < 64) { gkf[t] = bk[h * 64 + t]; gvf[t] = bv[h * 64 + t]; }
    __syncthreads();

    bf16x8 aq[2];
#pragma unroll
    for (int ks = 0; ks < 2; ++ks)
        aq[ks] = *(bf16x8*)(PsQ + (wave * 16 + l16) * 72 + ks * 32 + quad * 8);

    float s_g[4];
#pragma unroll
    for (int r = 0; r < 4; ++r) {
        int row = wave * 16 + quad * 4 + r;
        float part = 0.f;
#pragma unroll
        for (int dd = 0; dd < 4; ++dd) {
            int d = l16 * 4 + dd;
            part += b2f(PsQ[row * 72 + d]) * gkf[d];
        }
#pragma unroll
        for (int dsh = 1; dsh < 16; dsh <<= 1) part += __shfl_xor(part, dsh);
        s_g[r] = part;
    }

    f32x4 o_acc[4] = {};
    float m_run[4], l_run[4];
#pragma unroll
    for (int r = 0; r < 4; ++r) { m_run[r] = NEGF; l_run[r] = 0.f; }

    int kt_beg = (q0 == 0) ? 1 : 0;
    int kt_end = (q0 + 128 < 2048) ? 3 : 2;

    bf16x8 kreg[4], vreg[4];
    // prologue: issue K loads for the first tile (rows clamped)
    {
        int jb = q0 + (kt_beg - 1) * 128;
#pragma unroll
        for (int l = 0; l < 4; ++l) {
            int idx = l * 256 + t;
            int row = jb + (idx >> 3);
            row = (row < 0) ? 0 : ((row > 2047) ? 2047 : row);
            kreg[l] = *(const bf16x8*)(K + ((size_t)(bs_off + row)) * 3072 + (idx & 7) * 8);
        }
    }

    for (int kt = kt_beg; kt < kt_end; ++kt) {
        int jb = q0 + (kt - 1) * 128;
        // 1. K regs -> LDS (vmcnt wait on kreg hidden under prev PV)
#pragma unroll
        for (int l = 0; l < 4; ++l) {
            int idx = l * 256 + t;
            *(bf16x8*)(KV + (idx >> 3) * 72 + (idx & 7) * 8) = kreg[l];
        }
        // 2. issue V loads (land during QK^T + softmax); s clamped
#pragma unroll
        for (int l = 0; l < 4; ++l) {
            int idx = l * 256 + t;
            int s0 = jb + (idx & 15) * 8;
            s0 = (s0 < 0) ? 0 : ((s0 > 2040) ? 2040 : s0);
            vreg[l] = *(const bf16x8*)(Vg + ((size_t)(idx >> 4)) * 2048 + s0);
        }
        barrier_lds_only();   // K visible; V loads stay in flight

        f32x4 s_acc[8] = {};
#pragma unroll
        for (int ks = 0; ks < 2; ++ks) {
            bf16x8 bk8[8];
#pragma unroll
            for (int tj = 0; tj < 8; ++tj)
                bk8[tj] = *(bf16x8*)(KV + (tj * 16 + l16) * 72 + ks * 32 + quad * 8);
#pragma unroll
            for (int tj = 0; tj < 8; ++tj)
                s_acc[tj] = mfma16(aq[ks], bk8[tj], s_acc[tj]);
        }

        float negj[8]; int jcol[8];
#pragma unroll
        for (int tj = 0; tj < 8; ++tj) {
            jcol[tj] = jb + tj * 16 + l16;
            bool jv = (jcol[tj] >= 0) && (jcol[tj] < 2048);
            int jc = jv ? jcol[tj] : 0;
            negj[tj] = (!jv || (mask[bs_off + jc] != 0)) ? NEGF : 0.f;
        }
        float tmax[4];
#pragma unroll
        for (int r = 0; r < 4; ++r) tmax[r] = NEGF;
        int irow_base = q0 + wave * 16 + quad * 4;
#pragma unroll
        for (int tj = 0; tj < 8; ++tj)
#pragma unroll
            for (int r = 0; r < 4; ++r) {
                int dj = jcol[tj] - (irow_base + r);
                float sc = (dj >= -128 && dj <= 128) ? (s_acc[tj][r] + negj[tj]) : NEGF;
                s_acc[tj][r] = sc;
                tmax[r] = fmaxf(tmax[r], sc);
            }
#pragma unroll
        for (int r = 0; r < 4; ++r)
#pragma unroll
            for (int dsh = 1; dsh < 16; dsh <<= 1)
                tmax[r] = fmaxf(tmax[r], __shfl_xor(tmax[r], dsh));

        float alpha[4], lsum[4];
#pragma unroll
        for (int r = 0; r < 4; ++r) {
            float mnew = fmaxf(m_run[r], tmax[r]);
            alpha[r] = safe_exp(m_run[r] - mnew);
            m_run[r] = mnew;
            lsum[r] = 0.f;
        }
#pragma unroll
        for (int tj = 0; tj < 8; ++tj)
#pragma unroll
            for (int r = 0; r < 4; ++r) {
                float p = safe_exp(s_acc[tj][r] - m_run[r]);
                lsum[r] += p;
                PsQ[(wave * 16 + quad * 4 + r) * 136 + tj * 16 + l16] = f2b(p);
            }
#pragma unroll
        for (int r = 0; r < 4; ++r) {
#pragma unroll
            for (int dsh = 1; dsh < 16; dsh <<= 1) lsum[r] += __shfl_xor(lsum[r], dsh);
            l_run[r] = l_run[r] * alpha[r] + lsum[r];
        }
#pragma unroll
        for (int dj = 0; dj < 4; ++dj)
#pragma unroll
            for (int r = 0; r < 4; ++r) o_acc[dj][r] *= alpha[r];

        barrier_lds_only();   // all waves done reading KV-as-K

        // 6. V regs -> LDS (vmcnt wait on vreg hidden under softmax)
#pragma unroll
        for (int l = 0; l < 4; ++l) {
            int idx = l * 256 + t;
            *(bf16x8*)(KV + (idx >> 4) * 136 + (idx & 15) * 8) = vreg[l];
        }
        // 7. issue K loads for next tile (land during PV)
        if (kt + 1 < kt_end) {
            int jb2 = q0 + kt * 128;
#pragma unroll
            for (int l = 0; l < 4; ++l) {
                int idx = l * 256 + t;
                int row = jb2 + (idx >> 3);
                row = (row < 0) ? 0 : ((row > 2047) ? 2047 : row);
                kreg[l] = *(const bf16x8*)(K + ((size_t)(bs_off + row)) * 3072 + (idx & 7) * 8);
            }
        }
        barrier_lds_only();   // V visible; K loads stay in flight

#pragma unroll
        for (int ks = 0; ks < 4; ++ks) {
            bf16x8 ap, bv8[4];
            ap = *(bf16x8*)(PsQ + (wave * 16 + l16) * 136 + ks * 32 + quad * 8);
#pragma unroll
            for (int dj = 0; dj < 4; ++dj)
                bv8[dj] = *(bf16x8*)(KV + (dj * 16 + l16) * 136 + ks * 32 + quad * 8);
#pragma unroll
            for (int dj = 0; dj < 4; ++dj)
                o_acc[dj] = mfma16(ap, bv8[dj], o_acc[dj]);
        }
        barrier_lds_only();   // all waves done reading KV-as-V (next K write)
    }

    int irow_base = q0 + wave * 16 + quad * 4;
#pragma unroll
    for (int r = 0; r < 4; ++r) {
        int i = irow_base + r;
        float m2 = fmaxf(m_run[r], s_g[r]);
        float pg = safe_exp(s_g[r] - m2);
        float al = safe_exp(m_run[r] - m2);
        float l2 = l_run[r] * al + pg;
        float invl = 1.f / fmaxf(l2, 1e-30f);
        float qm = (mask[bs_off + i] > 0) ? 0.f : 1.f;
#pragma unroll
        for (int dj = 0; dj < 4; ++dj) {
            int d = dj * 16 + l16;
            float val = (o_acc[dj][r] * al + pg * gvf[d]) * invl * qm;
            attn[((size_t)(bs_off + i)) * 1024 + h * 64 + d] = f2b(val);
        }
    }
}

// ---------------------------------------------------------------------------
// y = LN(x + attn) * g + b ; writes bf16 (GEMM input) AND fp32 (residual).
// ---------------------------------------------------------------------------
__global__ __launch_bounds__(256) void resid_ln(
    const float* __restrict__ x, const short* __restrict__ attn,
    const float* __restrict__ g, const float* __restrict__ be,
    short* __restrict__ yb, float* __restrict__ yf)
{
    int row = blockIdx.x, t = threadIdx.x;
    int lane = t & 63, wave = t >> 6;
    const size_t base = (size_t)row * 1024;
    float v[4]; float s = 0.f, s2 = 0.f;
#pragma unroll
    for (int i = 0; i < 4; ++i) {
        int c = i * 256 + t;
        float val = x[base + c] + b2f(attn[base + c]);
        v[i] = val; s += val; s2 += val * val;
    }
#pragma unroll
    for (int off = 32; off > 0; off >>= 1) { s += __shfl_xor(s, off); s2 += __shfl_xor(s2, off); }
    __shared__ float red[8];
    if (lane == 0) { red[wave] = s; red[4 + wave] = s2; }
    __syncthreads();
    s  = red[0] + red[1] + red[2] + red[3];
    s2 = red[4] + red[5] + red[6] + red[7];
    float mu  = s * (1.f / 1024.f);
    float var = s2 * (1.f / 1024.f) - mu * mu;
    float inv = rsqrtf(fmaxf(var, 0.f) + 1e-5f);
#pragma unroll
    for (int i = 0; i < 4; ++i) {
        int c = i * 256 + t;
        float o = (v[i] - mu) * inv * g[c] + be[c];
        yb[base + c] = f2b(o);
        yf[base + c] = o;
    }
}

// ---------------------------------------------------------------------------
// workspace layout, units = bf16 elements (2 B). total 47M units = 94 MB.
// ---------------------------------------------------------------------------
static constexpr size_t MEG      = 1048576;
static constexpr size_t OFF_WQKV = 0;            // 3M  (3072x1024 bf16)
static constexpr size_t OFF_W1T  = 3 * MEG;      // 4M
static constexpr size_t OFF_W2T  = 7 * MEG;      // 4M
static constexpr size_t OFF_XB   = 11 * MEG;     // 4M
static constexpr size_t OFF_QKV  = 15 * MEG;     // 12M (4096x3072 bf16; V third unused)
static constexpr size_t OFF_VT   = 27 * MEG;     // 4M
static constexpr size_t OFF_ATT  = 31 * MEG;     // 4M
static constexpr size_t OFF_YN   = 35 * MEG;     // 4M (bf16)
static constexpr size_t OFF_YF   = 39 * MEG;     // 8M units = 4M fp32
static constexpr size_t OFF_H    = OFF_QKV;      // 16M, aliases QKV+VT (dead)

extern "C" void kernel_launch(void* const* d_in, const int* in_sizes, int n_in,
                              void* d_out, int out_size, void* d_ws, size_t ws_size,
                              hipStream_t stream) {
    (void)in_sizes; (void)n_in; (void)out_size; (void)ws_size;
    const float* x    = (const float*)d_in[0];
    const int*   mask = (const int*)  d_in[1];
    const float* wq   = (const float*)d_in[2];
    const float* bq   = (const float*)d_in[3];
    const float* wk   = (const float*)d_in[4];
    const float* bk   = (const float*)d_in[5];
    const float* wv   = (const float*)d_in[6];
    const float* bv   = (const float*)d_in[7];
    // d_in[8..13] (global-query branch) are provably dead for the output
    const float* lng  = (const float*)d_in[14];
    const float* lnb  = (const float*)d_in[15];
    const float* w1   = (const float*)d_in[16];
    const float* b1   = (const float*)d_in[17];
    const float* w2   = (const float*)d_in[18];
    const float* b2   = (const float*)d_in[19];
    short* ws  = (short*)d_ws;
    float* out = (float*)d_out;

    dim3 tb(32, 8);
    cvt_transpose_qkv<<<dim3(32, 32, 3), tb, 0, stream>>>(wq, wk, wv, ws + OFF_WQKV);
    cvt_transpose<<<dim3(128, 32), tb, 0, stream>>>(w1, ws + OFF_W1T, 1024, 4096);
    cvt_transpose<<<dim3(32, 128), tb, 0, stream>>>(w2, ws + OFF_W2T, 4096, 1024);
    cvt_f32_bf16<<<4096, 256, 0, stream>>>(x, ws + OFF_XB, 4194304);

    // QKV = x @ [wq|wk|wv] + [bq|bk|bv]; Q scaled 1/8; V staged -> Vt fused
    gemm_bt<<<dim3(32, 24), 256, 0, stream>>>(ws + OFF_XB, ws + OFF_WQKV,
                                              bq, bk, bv,
                                              ws + OFF_QKV, ws + OFF_VT,
                                              4096, 3072, 1024, 0.125f, 0);

    // q-chunk 64: grid 32 chunks x 16 heads x 2 batches = 1024 blocks
    attn_kernel<<<1024, 256, 36352, stream>>>(ws + OFF_QKV, ws + OFF_VT,
                                              mask, bk, bv, ws + OFF_ATT);

    resid_ln<<<4096, 256, 0, stream>>>(x, ws + OFF_ATT, lng, lnb,
                                       ws + OFF_YN, (float*)(ws + OFF_YF));

    // h = gelu(y@w1 + b1)
    gemm_bt<<<dim3(32, 32), 256, 0, stream>>>(ws + OFF_YN, ws + OFF_W1T,
                                              b1, nullptr, nullptr,
                                              ws + OFF_H, nullptr,
                                              4096, 4096, 1024, 1.0f, 1);
    // out = y + h@w2 + b2 (64^2 tile, dbuf, counted vmcnt, natural order)
    gemm64_db<<<dim3(64, 16), 256, 0, stream>>>(ws + OFF_H, ws + OFF_W2T,
                                                b2, (const float*)(ws + OFF_YF),
                                                out, 4096, 1024, 4096);
}

// Round 11
// 330.076 us; speedup vs baseline: 1.0480x; 1.0480x over previous
//
#include <hip/hip_runtime.h>

// ---------------------------------------------------------------------------
// HFLongFormerSelfAttentionBlock — MI355X implementation (round 17)
//
// I/O fp32; internal bf16 MFMA, fp32 accumulation/epilogues.
// Round-17: attn staging rewritten. r16's q64 kernel spilled ~256 B/thread
// (rocprof: FETCH +68 MB, WRITE +64 MB vs r7 — a scratch round trip; kernel
// became HBM-bound on its own spills at 173 MB / 3 TB/s ~= 57.5us). Fix:
// K/V staged via global_load_lds + counted vmcnt(4) (gemm64_db pattern) —
// deletes kreg/vreg (-32 VGPR) and the LDS-write pass, keeps T14 overlap
// (K lands under PV, V lands under QK^T+softmax, never drained mid-loop).
// global_load_lds needs linear LDS dest -> K [128][64] / V [64][128]
// unpadded with XOR swizzle via pre-swizzled GLOBAL source (gemm_bt's
// proven conflict-free pattern). LDS 50.7 KB -> 3 blocks/CU, lb(256,3),
// no spill. GEMMs unchanged from round 16.
// ---------------------------------------------------------------------------

using bf16x8 = __attribute__((ext_vector_type(8))) short;
using bf16x4 = __attribute__((ext_vector_type(4))) short;
using f32x4  = __attribute__((ext_vector_type(4))) float;

__device__ __forceinline__ float b2f(short s) {
    return __uint_as_float(((unsigned int)(unsigned short)s) << 16);
}
__device__ __forceinline__ short f2b(float f) {
    unsigned int u = __float_as_uint(f);
    u += 0x7fffu + ((u >> 16) & 1u);   // round-to-nearest-even
    return (short)(u >> 16);
}
__device__ __forceinline__ f32x4 mfma16(bf16x8 a, bf16x8 b, f32x4 c) {
    return __builtin_amdgcn_mfma_f32_16x16x32_bf16(a, b, c, 0, 0, 0);
}
// args are always <= 0 here (online-softmax differences); __expf -> v_exp_f32
__device__ __forceinline__ float safe_exp(float x) {
    return __expf((x <= 0.f) ? x : 0.f);
}
// gelu(v) = 0.5 v (1 + erf(v/sqrt2)); erf via A&S 7.1.25 (|err| <= 2.5e-5,
// branch-free: rcp + exp + 5 fma). 100x below bf16 output quantization.
__device__ __forceinline__ float fast_gelu(float v) {
    float z  = fabsf(v) * 0.70710678118f;
    float t  = __builtin_amdgcn_rcpf(fmaf(0.47047f, z, 1.f));
    float e  = __expf(-z * z);
    float p  = t * fmaf(t, fmaf(t, 0.7478556f, -0.0958798f), 0.3480242f);
    float er = fmaf(-p, e, 1.f);                  // erf(|z|)
    er = (v < 0.f) ? -er : er;
    return 0.5f * v * (1.f + er);
}
// async global->LDS, 16 B per lane; LDS dest = wave-uniform base + lane*16
__device__ __forceinline__ void load_lds16(const short* g, short* l) {
    __builtin_amdgcn_global_load_lds((const __attribute__((address_space(1))) void*)g,
                                     (__attribute__((address_space(3))) void*)l, 16, 0, 0);
}
// raw barrier: LDS ops drained for visibility; in-flight GLOBAL loads are
// NOT drained (unlike __syncthreads' vmcnt(0)) — the async-staging enabler.
__device__ __forceinline__ void barrier_lds_only() {
    asm volatile("s_waitcnt lgkmcnt(0)" ::: "memory");
    __builtin_amdgcn_s_barrier();
    asm volatile("" ::: "memory");
}
#define NEGF (-3.0e38f)

// ---------------------------------------------------------------------------
// fp32 -> bf16 elementwise convert (n multiple of 1024). grid n/1024, 256 thr
// ---------------------------------------------------------------------------
__global__ void cvt_f32_bf16(const float* __restrict__ in, short* __restrict__ out, int n) {
    int i = (blockIdx.x * 256 + threadIdx.x) * 4;
    f32x4 v = *(const f32x4*)(in + i);
    bf16x4 o;
#pragma unroll
    for (int j = 0; j < 4; ++j) o[j] = f2b(v[j]);
    *(bf16x4*)(out + i) = o;
}

// ---------------------------------------------------------------------------
// fp32 in, bf16 transposed out: out[c][r] = in[r][c], in is R x C.
// grid (C/32, R/32), block (32,8)
// ---------------------------------------------------------------------------
__global__ void cvt_transpose(const float* __restrict__ in, short* __restrict__ out,
                              int R, int C) {
    __shared__ short tile[32][33];
    int bx = blockIdx.x * 32, by = blockIdx.y * 32;
    int tx = threadIdx.x, ty = threadIdx.y;
    for (int i = ty; i < 32; i += 8)
        tile[i][tx] = f2b(in[(size_t)(by + i) * C + bx + tx]);
    __syncthreads();
    for (int i = ty; i < 32; i += 8)
        out[(size_t)(bx + i) * R + by + tx] = tile[tx][i];
}

// wq/wk/wv (each 1024x1024 fp32) -> WQKVT (3072x1024 bf16, = [wq^T;wk^T;wv^T])
__global__ void cvt_transpose_qkv(const float* __restrict__ wq, const float* __restrict__ wk,
                                  const float* __restrict__ wv, short* __restrict__ out) {
    __shared__ short tile[32][33];
    const float* in = (blockIdx.z == 0) ? wq : (blockIdx.z == 1) ? wk : wv;
    short* dst = out + (size_t)blockIdx.z * 1024 * 1024;
    int bx = blockIdx.x * 32, by = blockIdx.y * 32;
    int tx = threadIdx.x, ty = threadIdx.y;
    for (int i = ty; i < 32; i += 8)
        tile[i][tx] = f2b(in[(size_t)(by + i) * 1024 + bx + tx]);
    __syncthreads();
    for (int i = ty; i < 32; i += 8)
        dst[(size_t)(bx + i) * 1024 + by + tx] = tile[tx][i];
}

// ---------------------------------------------------------------------------
// GEMM 128x128, BK=64, XOR-swizzled LDS k-chunks. NATURAL block order.
// mode 0: QKV — bias by col segment, Q scaled, V staged+transposed -> Vt
// mode 1: C = bf16(gelu(acc + bias0[col]))
// Epilogue always stages the tile in LDS, then coalesced 16-B stores.
// ---------------------------------------------------------------------------
__global__ __launch_bounds__(256, 4) void gemm_bt(
    const short* __restrict__ A, const short* __restrict__ Bt,
    const float* __restrict__ bias0, const float* __restrict__ bias1,
    const float* __restrict__ bias2,
    short* __restrict__ C, short* __restrict__ Vt,
    int M, int N, int K, float scale, int mode)
{
    __shared__ short sh[128 * 136];   // 34.8 KB; main loop uses first 16K shorts
    short* As = sh;
    short* Bs = sh + 8192;
    int m0 = blockIdx.x * 128, n0 = blockIdx.y * 128;
    int t = threadIdx.x;
    int wave = t >> 6, lane = t & 63, quad = lane >> 4, l16 = lane & 15;
    int wr = (wave >> 1) * 64, wc = (wave & 1) * 64;

    // staging pointers: 4 chunks per wave per buffer
    const short* ap[4]; const short* bp[4]; short* la[4]; short* lb[4];
    int gk = (((lane & 7) ^ (lane >> 3)) * 8);
#pragma unroll
    for (int l = 0; l < 4; ++l) {
        int c = wave * 4 + l;
        int row = c * 8 + (lane >> 3);
        ap[l] = A  + (size_t)(m0 + row) * K + gk;
        bp[l] = Bt + (size_t)(n0 + row) * K + gk;
        la[l] = As + c * 512;
        lb[l] = Bs + c * 512;
    }
    int sw = l16 & 7;   // frag-read swizzle key

    f32x4 acc[4][4] = {};
    for (int k0 = 0; k0 < K; k0 += 64) {
#pragma unroll
        for (int l = 0; l < 4; ++l) { load_lds16(ap[l] + k0, la[l]); load_lds16(bp[l] + k0, lb[l]); }
        __syncthreads();
#pragma unroll
        for (int ks = 0; ks < 2; ++ks) {
            int slot = ((ks * 4 + quad) ^ sw) * 8;
            bf16x8 af[4], bfr[4];
#pragma unroll
            for (int i = 0; i < 4; ++i)
                af[i] = *(bf16x8*)(As + (wr + i * 16 + l16) * 64 + slot);
#pragma unroll
            for (int j = 0; j < 4; ++j)
                bfr[j] = *(bf16x8*)(Bs + (wc + j * 16 + l16) * 64 + slot);
#pragma unroll
            for (int i = 0; i < 4; ++i)
#pragma unroll
                for (int j = 0; j < 4; ++j)
                    acc[i][j] = mfma16(af[i], bfr[j], acc[i][j]);
        }
        __syncthreads();
    }
    // after final barrier, all LDS reads are done -> sh reusable for staging

    int seg0 = n0 >> 10;   // tiles are 128-aligned: never straddle a segment
    if (mode == 1 || seg0 < 2) {
        // ---- stage bf16 tile in LDS: sh[row*136 + col], row/col in [0,128)
        if (mode == 1) {
#pragma unroll
            for (int j = 0; j < 4; ++j) {
                int col = n0 + wc + j * 16 + l16;
                float bs = bias0[col];
#pragma unroll
                for (int i = 0; i < 4; ++i)
#pragma unroll
                    for (int r = 0; r < 4; ++r) {
                        float v = fast_gelu(acc[i][j][r] + bs);
                        sh[(wr + i * 16 + quad * 4 + r) * 136 + wc + j * 16 + l16] = f2b(v);
                    }
            }
        } else {
            float sc = (seg0 == 0) ? scale : 1.0f;
            const float* bpt = (seg0 == 0) ? bias0 : bias1;
#pragma unroll
            for (int j = 0; j < 4; ++j) {
                int col = n0 + wc + j * 16 + l16;
                float bs = bpt[col & 1023];
#pragma unroll
                for (int i = 0; i < 4; ++i)
#pragma unroll
                    for (int r = 0; r < 4; ++r)
                        sh[(wr + i * 16 + quad * 4 + r) * 136 + wc + j * 16 + l16] =
                            f2b((acc[i][j][r] + bs) * sc);
            }
        }
        __syncthreads();
        // ---- coalesced write-out: 2 threads per row, 8 x 16 B each
        int row = t >> 1, half = t & 1;
        const short* src = sh + row * 136 + half * 64;
        short* dst = C + (size_t)(m0 + row) * N + n0 + half * 64;
#pragma unroll
        for (int cgk = 0; cgk < 8; ++cgk)
            *(bf16x8*)(dst + cgk * 8) = *(const bf16x8*)(src + cgk * 8);
    } else {
        // ---- V part: stage TRANSPOSED in LDS (sh[c*136 + row]), then write
        //      Vt (b, h, d, s) with 16-B chunks coalesced along s.
#pragma unroll
        for (int j = 0; j < 4; ++j) {
            int cl = wc + j * 16 + l16;                 // local col in [0,128)
            float bs = bias2[(n0 & 1023) + cl];
#pragma unroll
            for (int i = 0; i < 4; ++i)
#pragma unroll
                for (int r = 0; r < 4; ++r)
                    sh[cl * 136 + wr + i * 16 + quad * 4 + r] = f2b(acc[i][j][r] + bs);
        }
        __syncthreads();
        int h0 = (n0 & 1023) >> 6;                      // first head of tile
        int bb = m0 >> 11, s0 = m0 & 2047;
        int sc = t & 15;                                // s-chunk within tile
#pragma unroll
        for (int cgk = 0; cgk < 8; ++cgk) {
            int cl = (t >> 4) + cgk * 16;               // local col
            int h = h0 + (cl >> 6), d = cl & 63;
            *(bf16x8*)(Vt + (((size_t)(bb * 16 + h)) * 64 + d) * 2048 + s0 + sc * 8) =
                *(const bf16x8*)(sh + cl * 136 + sc * 8);
        }
    }
}

// ---------------------------------------------------------------------------
// MLP2 GEMM: 64x64, BK=64, XOR swizzle, double-buffered with counted vmcnt(4).
// NATURAL block order (A partitioned m%8 across XCD L2s). 4 blocks/CU —
// measured-best config for this grid-constrained shape (r6: 59us).
// Cf = A@B + bias + resf (fp32 out). grid (M/64, N/64), 256 thr.
// ---------------------------------------------------------------------------
__global__ __launch_bounds__(256, 4) void gemm64_db(
    const short* __restrict__ A, const short* __restrict__ Bt,
    const float* __restrict__ bias, const float* __restrict__ resf,
    float* __restrict__ Cf, int M, int N, int K)
{
    __shared__ short As[2][64 * 64];
    __shared__ short Bs[2][64 * 64];
    int m0 = blockIdx.x * 64, n0 = blockIdx.y * 64;
    int t = threadIdx.x;
    int wave = t >> 6, lane = t & 63, quad = lane >> 4, l16 = lane & 15;
    int wr = (wave >> 1) * 32, wc = (wave & 1) * 32;

    const short* ap[2]; const short* bp[2]; int lo[2];
    int gk = (((lane & 7) ^ (lane >> 3)) * 8);
#pragma unroll
    for (int l = 0; l < 2; ++l) {
        int c = wave * 2 + l;
        int row = c * 8 + (lane >> 3);
        ap[l] = A  + (size_t)(m0 + row) * K + gk;
        bp[l] = Bt + (size_t)(n0 + row) * K + gk;
        lo[l] = c * 512;
    }
    int sw = l16 & 7;

    const int nt = K >> 6;
#pragma unroll
    for (int l = 0; l < 2; ++l) { load_lds16(ap[l], &As[0][lo[l]]); load_lds16(bp[l], &Bs[0][lo[l]]); }

    f32x4 acc[2][2] = {};
    for (int ti = 0; ti < nt; ++ti) {
        int cur = ti & 1;
        if (ti + 1 < nt) {
            int k0 = (ti + 1) << 6;
#pragma unroll
            for (int l = 0; l < 2; ++l) {
                load_lds16(ap[l] + k0, &As[cur ^ 1][lo[l]]);
                load_lds16(bp[l] + k0, &Bs[cur ^ 1][lo[l]]);
            }
            asm volatile("s_waitcnt vmcnt(4)" ::: "memory");  // wait cur's loads only
        } else {
            asm volatile("s_waitcnt vmcnt(0)" ::: "memory");
        }
        __builtin_amdgcn_s_barrier();
        asm volatile("" ::: "memory");

        const short* as = &As[cur][0];
        const short* bs = &Bs[cur][0];
#pragma unroll
        for (int ks = 0; ks < 2; ++ks) {
            int slot = ((ks * 4 + quad) ^ sw) * 8;
            bf16x8 af[2], bfr[2];
#pragma unroll
            for (int i = 0; i < 2; ++i)
                af[i] = *(bf16x8*)(as + (wr + i * 16 + l16) * 64 + slot);
#pragma unroll
            for (int j = 0; j < 2; ++j)
                bfr[j] = *(bf16x8*)(bs + (wc + j * 16 + l16) * 64 + slot);
#pragma unroll
            for (int i = 0; i < 2; ++i)
#pragma unroll
                for (int j = 0; j < 2; ++j)
                    acc[i][j] = mfma16(af[i], bfr[j], acc[i][j]);
        }
        asm volatile("" ::: "memory");
        __builtin_amdgcn_s_barrier();   // protect buf cur^1 before next stage
    }

#pragma unroll
    for (int j = 0; j < 2; ++j) {
        int col = n0 + wc + j * 16 + l16;
        float bs = bias[col];
#pragma unroll
        for (int i = 0; i < 2; ++i) {
#pragma unroll
            for (int r = 0; r < 4; ++r) {
                int row = m0 + wr + i * 16 + quad * 4 + r;
                Cf[(size_t)row * N + col] = acc[i][j][r] + bs + resf[(size_t)row * N + col];
            }
        }
    }
}

// ---------------------------------------------------------------------------
// Windowed attention with global column. Round-17: q-chunk 64, K/V staged by
// global_load_lds into linear LDS (K [128][64], V [64][128]) with the
// pre-swizzled-global-source XOR pattern; counted vmcnt(4) keeps one tile's
// loads in flight across barriers (K lands under PV, V under QK^T+softmax).
// No reg staging -> no spills. LDS 50688 B -> 3 blocks/CU.
// Boundary tiles: load rows/cols clamped; jcol outside [0,2048) masked to
// NEGF (=> P=0, garbage K/V contributes nothing).
// smem: P/Q 17408 (Q 64x72, P 64x136) | K 16384 | V 16384 | gkf/gvf 512
// ---------------------------------------------------------------------------
__global__ __launch_bounds__(256, 3) void attn_kernel(
    const short* __restrict__ QKV, const short* __restrict__ Vt,
    const int* __restrict__ mask,
    const float* __restrict__ bk, const float* __restrict__ bv,
    short* __restrict__ attn)
{
    extern __shared__ char smem[];
    short* PsQ = (short*)smem;               // Q [64][72] then P [64][136]
    short* Ks  = (short*)(smem + 17408);     // K  [128][64] swizzled chunks
    short* Vs  = (short*)(smem + 33792);     // V  [64][128] swizzled chunks
    float* gkf = (float*)(smem + 50176);
    float* gvf = (float*)(smem + 50432);

    int blk = blockIdx.x;
    int c = blk & 31, h = (blk >> 5) & 15, b = blk >> 9;
    int t = threadIdx.x;
    int wave = t >> 6, lane = t & 63, quad = lane >> 4, l16 = lane & 15;
    int q0 = c * 64;
    const int bs_off = b * 2048;
    const short* Q = QKV + h * 64;
    const short* K = QKV + 1024 + h * 64;
    const short* Vg = Vt + (size_t)(b * 16 + h) * 64 * 2048;
    int sw = l16 & 7;
    int wub = (t & 192) * 8;                 // wave-uniform LDS chunk base

    // Q stage: 64 rows x 64 cols (72-stride, scalar-read later -> pad ok)
#pragma unroll
    for (int l = 0; l < 2; ++l) {
        int idx = l * 256 + t;
        int p = idx >> 3, dc = (idx & 7) * 8;
        *(bf16x8*)(PsQ + p * 72 + dc) =
            *(const bf16x8*)(Q + ((size_t)(bs_off + q0 + p)) * 3072 + dc);
    }
    if (t < 64) { gkf[t] = bk[h * 64 + t]; gvf[t] = bv[h * 64 + t]; }
    __syncthreads();

    bf16x8 aq[2];
#pragma unroll
    for (int ks = 0; ks < 2; ++ks)
        aq[ks] = *(bf16x8*)(PsQ + (wave * 16 + l16) * 72 + ks * 32 + quad * 8);

    float s_g[4];
#pragma unroll
    for (int r = 0; r < 4; ++r) {
        int row = wave * 16 + quad * 4 + r;
        float part = 0.f;
#pragma unroll
        for (int dd = 0; dd < 4; ++dd) {
            int d = l16 * 4 + dd;
            part += b2f(PsQ[row * 72 + d]) * gkf[d];
        }
#pragma unroll
        for (int dsh = 1; dsh < 16; dsh <<= 1) part += __shfl_xor(part, dsh);
        s_g[r] = part;
    }

    f32x4 o_acc[4] = {};
    float m_run[4], l_run[4];
#pragma unroll
    for (int r = 0; r < 4; ++r) { m_run[r] = NEGF; l_run[r] = 0.f; }

    int kt_beg = (q0 == 0) ? 1 : 0;
    int kt_end = (q0 + 128 < 2048) ? 3 : 2;

    // staging issuers: linear LDS dest (wave-uniform base + lane*16),
    // per-lane global source with pre-swizzled chunk (read undoes the XOR)
#define ISSUE_K(JB)                                                          \
    {                                                                        \
        _Pragma("unroll")                                                    \
        for (int l = 0; l < 4; ++l) {                                        \
            int row = l * 32 + (t >> 3);                                     \
            int rg = (JB) + row;                                             \
            rg = (rg < 0) ? 0 : ((rg > 2047) ? 2047 : rg);                   \
            load_lds16(K + (size_t)(bs_off + rg) * 3072 +                    \
                           (((t & 7) ^ (row & 7)) * 8),                      \
                       Ks + l * 2048 + wub);                                 \
        }                                                                    \
    }
#define ISSUE_V(JB)                                                          \
    {                                                                        \
        _Pragma("unroll")                                                    \
        for (int l = 0; l < 4; ++l) {                                        \
            int d = l * 16 + (t >> 4);                                       \
            int sg = (JB) + (((t & 15) ^ (d & 7)) * 8);                      \
            sg = (sg < 0) ? 0 : ((sg > 2040) ? 2040 : sg);                   \
            load_lds16(Vg + (size_t)d * 2048 + sg,                           \
                       Vs + l * 2048 + wub);                                 \
        }                                                                    \
    }

    // prologue: issue K[beg] then V[beg]  (outstanding: K 4, V 4 per thread)
    {
        int jb0 = q0 + (kt_beg - 1) * 128;
        ISSUE_K(jb0);
        ISSUE_V(jb0);
    }

    for (int kt = kt_beg; kt < kt_end; ++kt) {
        int jb = q0 + (kt - 1) * 128;
        // K[kt] landed (4 V loads may remain in flight)
        asm volatile("s_waitcnt vmcnt(4)" ::: "memory");
        __builtin_amdgcn_s_barrier();
        asm volatile("" ::: "memory");

        f32x4 s_acc[8] = {};
#pragma unroll
        for (int ks = 0; ks < 2; ++ks) {
            int slot = ((ks * 4 + quad) ^ sw) * 8;
            bf16x8 bk8[8];
#pragma unroll
            for (int tj = 0; tj < 8; ++tj)
                bk8[tj] = *(bf16x8*)(Ks + (tj * 16 + l16) * 64 + slot);
#pragma unroll
            for (int tj = 0; tj < 8; ++tj)
                s_acc[tj] = mfma16(aq[ks], bk8[tj], s_acc[tj]);
        }

        float negj[8]; int jcol[8];
#pragma unroll
        for (int tj = 0; tj < 8; ++tj) {
            jcol[tj] = jb + tj * 16 + l16;
            bool jv = (jcol[tj] >= 0) && (jcol[tj] < 2048);
            int jc = jv ? jcol[tj] : 0;
            negj[tj] = (!jv || (mask[bs_off + jc] != 0)) ? NEGF : 0.f;
        }
        float tmax[4];
#pragma unroll
        for (int r = 0; r < 4; ++r) tmax[r] = NEGF;
        int irow_base = q0 + wave * 16 + quad * 4;
#pragma unroll
        for (int tj = 0; tj < 8; ++tj)
#pragma unroll
            for (int r = 0; r < 4; ++r) {
                int dj = jcol[tj] - (irow_base + r);
                float sc = (dj >= -128 && dj <= 128) ? (s_acc[tj][r] + negj[tj]) : NEGF;
                s_acc[tj][r] = sc;
                tmax[r] = fmaxf(tmax[r], sc);
            }
#pragma unroll
        for (int r = 0; r < 4; ++r)
#pragma unroll
            for (int dsh = 1; dsh < 16; dsh <<= 1)
                tmax[r] = fmaxf(tmax[r], __shfl_xor(tmax[r], dsh));

        float alpha[4], lsum[4];
#pragma unroll
        for (int r = 0; r < 4; ++r) {
            float mnew = fmaxf(m_run[r], tmax[r]);
            alpha[r] = safe_exp(m_run[r] - mnew);
            m_run[r] = mnew;
            lsum[r] = 0.f;
        }
#pragma unroll
        for (int tj = 0; tj < 8; ++tj)
#pragma unroll
            for (int r = 0; r < 4; ++r) {
                float p = safe_exp(s_acc[tj][r] - m_run[r]);
                lsum[r] += p;
                PsQ[(wave * 16 + quad * 4 + r) * 136 + tj * 16 + l16] = f2b(p);
            }
#pragma unroll
        for (int r = 0; r < 4; ++r) {
#pragma unroll
            for (int dsh = 1; dsh < 16; dsh <<= 1) lsum[r] += __shfl_xor(lsum[r], dsh);
            l_run[r] = l_run[r] * alpha[r] + lsum[r];
        }
#pragma unroll
        for (int dj = 0; dj < 4; ++dj)
#pragma unroll
            for (int r = 0; r < 4; ++r) o_acc[dj][r] *= alpha[r];

        barrier_lds_only();   // all waves done reading Ks; P visible

        // K region free: issue next K (lands during PV)
        if (kt + 1 < kt_end) {
            ISSUE_K(jb + 128);
            asm volatile("s_waitcnt vmcnt(4)" ::: "memory");  // V[kt] landed
        } else {
            asm volatile("s_waitcnt vmcnt(0)" ::: "memory");
        }
        __builtin_amdgcn_s_barrier();
        asm volatile("" ::: "memory");

#pragma unroll
        for (int ks = 0; ks < 4; ++ks) {
            int slot = ((ks * 4 + quad) ^ sw) * 8;
            bf16x8 ap = *(bf16x8*)(PsQ + (wave * 16 + l16) * 136 + ks * 32 + quad * 8);
            bf16x8 bv8[4];
#pragma unroll
            for (int dj = 0; dj < 4; ++dj)
                bv8[dj] = *(bf16x8*)(Vs + (dj * 16 + l16) * 128 + slot);
#pragma unroll
            for (int dj = 0; dj < 4; ++dj)
                o_acc[dj] = mfma16(ap, bv8[dj], o_acc[dj]);
        }
        barrier_lds_only();   // all waves done reading Vs

        // V region free: issue next V (lands during next QK^T + softmax)
        if (kt + 1 < kt_end) ISSUE_V(jb + 128);
    }

    int irow_base = q0 + wave * 16 + quad * 4;
#pragma unroll
    for (int r = 0; r < 4; ++r) {
        int i = irow_base + r;
        float m2 = fmaxf(m_run[r], s_g[r]);
        float pg = safe_exp(s_g[r] - m2);
        float al = safe_exp(m_run[r] - m2);
        float l2 = l_run[r] * al + pg;
        float invl = 1.f / fmaxf(l2, 1e-30f);
        float qm = (mask[bs_off + i] > 0) ? 0.f : 1.f;
#pragma unroll
        for (int dj = 0; dj < 4; ++dj) {
            int d = dj * 16 + l16;
            float val = (o_acc[dj][r] * al + pg * gvf[d]) * invl * qm;
            attn[((size_t)(bs_off + i)) * 1024 + h * 64 + d] = f2b(val);
        }
    }
#undef ISSUE_K
#undef ISSUE_V
}

// ---------------------------------------------------------------------------
// y = LN(x + attn) * g + b ; writes bf16 (GEMM input) AND fp32 (residual).
// ---------------------------------------------------------------------------
__global__ __launch_bounds__(256) void resid_ln(
    const float* __restrict__ x, const short* __restrict__ attn,
    const float* __restrict__ g, const float* __restrict__ be,
    short* __restrict__ yb, float* __restrict__ yf)
{
    int row = blockIdx.x, t = threadIdx.x;
    int lane = t & 63, wave = t >> 6;
    const size_t base = (size_t)row * 1024;
    float v[4]; float s = 0.f, s2 = 0.f;
#pragma unroll
    for (int i = 0; i < 4; ++i) {
        int c = i * 256 + t;
        float val = x[base + c] + b2f(attn[base + c]);
        v[i] = val; s += val; s2 += val * val;
    }
#pragma unroll
    for (int off = 32; off > 0; off >>= 1) { s += __shfl_xor(s, off); s2 += __shfl_xor(s2, off); }
    __shared__ float red[8];
    if (lane == 0) { red[wave] = s; red[4 + wave] = s2; }
    __syncthreads();
    s  = red[0] + red[1] + red[2] + red[3];
    s2 = red[4] + red[5] + red[6] + red[7];
    float mu  = s * (1.f / 1024.f);
    float var = s2 * (1.f / 1024.f) - mu * mu;
    float inv = rsqrtf(fmaxf(var, 0.f) + 1e-5f);
#pragma unroll
    for (int i = 0; i < 4; ++i) {
        int c = i * 256 + t;
        float o = (v[i] - mu) * inv * g[c] + be[c];
        yb[base + c] = f2b(o);
        yf[base + c] = o;
    }
}

// ---------------------------------------------------------------------------
// workspace layout, units = bf16 elements (2 B). total 47M units = 94 MB.
// ---------------------------------------------------------------------------
static constexpr size_t MEG      = 1048576;
static constexpr size_t OFF_WQKV = 0;            // 3M  (3072x1024 bf16)
static constexpr size_t OFF_W1T  = 3 * MEG;      // 4M
static constexpr size_t OFF_W2T  = 7 * MEG;      // 4M
static constexpr size_t OFF_XB   = 11 * MEG;     // 4M
static constexpr size_t OFF_QKV  = 15 * MEG;     // 12M (4096x3072 bf16; V third unused)
static constexpr size_t OFF_VT   = 27 * MEG;     // 4M
static constexpr size_t OFF_ATT  = 31 * MEG;     // 4M
static constexpr size_t OFF_YN   = 35 * MEG;     // 4M (bf16)
static constexpr size_t OFF_YF   = 39 * MEG;     // 8M units = 4M fp32
static constexpr size_t OFF_H    = OFF_QKV;      // 16M, aliases QKV+VT (dead)

extern "C" void kernel_launch(void* const* d_in, const int* in_sizes, int n_in,
                              void* d_out, int out_size, void* d_ws, size_t ws_size,
                              hipStream_t stream) {
    (void)in_sizes; (void)n_in; (void)out_size; (void)ws_size;
    const float* x    = (const float*)d_in[0];
    const int*   mask = (const int*)  d_in[1];
    const float* wq   = (const float*)d_in[2];
    const float* bq   = (const float*)d_in[3];
    const float* wk   = (const float*)d_in[4];
    const float* bk   = (const float*)d_in[5];
    const float* wv   = (const float*)d_in[6];
    const float* bv   = (const float*)d_in[7];
    // d_in[8..13] (global-query branch) are provably dead for the output
    const float* lng  = (const float*)d_in[14];
    const float* lnb  = (const float*)d_in[15];
    const float* w1   = (const float*)d_in[16];
    const float* b1   = (const float*)d_in[17];
    const float* w2   = (const float*)d_in[18];
    const float* b2   = (const float*)d_in[19];
    short* ws  = (short*)d_ws;
    float* out = (float*)d_out;

    dim3 tb(32, 8);
    cvt_transpose_qkv<<<dim3(32, 32, 3), tb, 0, stream>>>(wq, wk, wv, ws + OFF_WQKV);
    cvt_transpose<<<dim3(128, 32), tb, 0, stream>>>(w1, ws + OFF_W1T, 1024, 4096);
    cvt_transpose<<<dim3(32, 128), tb, 0, stream>>>(w2, ws + OFF_W2T, 4096, 1024);
    cvt_f32_bf16<<<4096, 256, 0, stream>>>(x, ws + OFF_XB, 4194304);

    // QKV = x @ [wq|wk|wv] + [bq|bk|bv]; Q scaled 1/8; V staged -> Vt fused
    gemm_bt<<<dim3(32, 24), 256, 0, stream>>>(ws + OFF_XB, ws + OFF_WQKV,
                                              bq, bk, bv,
                                              ws + OFF_QKV, ws + OFF_VT,
                                              4096, 3072, 1024, 0.125f, 0);

    // q-chunk 64: grid 32 chunks x 16 heads x 2 batches = 1024 blocks
    attn_kernel<<<1024, 256, 50688, stream>>>(ws + OFF_QKV, ws + OFF_VT,
                                              mask, bk, bv, ws + OFF_ATT);

    resid_ln<<<4096, 256, 0, stream>>>(x, ws + OFF_ATT, lng, lnb,
                                       ws + OFF_YN, (float*)(ws + OFF_YF));

    // h = gelu(y@w1 + b1)
    gemm_bt<<<dim3(32, 32), 256, 0, stream>>>(ws + OFF_YN, ws + OFF_W1T,
                                              b1, nullptr, nullptr,
                                              ws + OFF_H, nullptr,
                                              4096, 4096, 1024, 1.0f, 1);
    // out = y + h@w2 + b2 (64^2 tile, dbuf, counted vmcnt, natural order)
    gemm64_db<<<dim3(64, 16), 256, 0, stream>>>(ws + OFF_H, ws + OFF_W2T,
                                                b2, (const float*)(ws + OFF_YF),
                                                out, 4096, 1024, 4096);
}

// Round 12
// 319.264 us; speedup vs baseline: 1.0835x; 1.0339x over previous
//
#include <hip/hip_runtime.h>

// ---------------------------------------------------------------------------
// HFLongFormerSelfAttentionBlock — MI355X implementation (round 18)
//
// I/O fp32; internal bf16 MFMA, fp32 accumulation/epilogues.
// Round-18:
//  1. prep_all: the 4 preprocessing kernels (qkv/w1/w2 transpose + x convert)
//     fused into ONE dispatch (flat grid 15360, block-id range dispatch,
//     wave-uniform branches). 9 -> 6 launches: component-sum vs total showed
//     ~80-90us of inter-launch overhead (~10us/launch).
//  2. MLP2 -> gemm64w2_db: 64x64 block, TWO waves (128 thr), wave tile 32x64
//     (acc[2][4], 21.8 FLOP/LDS-byte vs 16 at 4-wave 64^2), dbuf + counted
//     vmcnt(8), 4 blocks/CU. Tests the unexplored (8 waves/CU, high-F/B,
//     4-block granularity) quadrant; model predicts ~49us. If >=57us, the
//     quadrant closes and 64^2 is the plateau (revert next round).
// attn/gemm_bt/resid_ln unchanged from round 17.
// ---------------------------------------------------------------------------

using bf16x8 = __attribute__((ext_vector_type(8))) short;
using bf16x4 = __attribute__((ext_vector_type(4))) short;
using f32x4  = __attribute__((ext_vector_type(4))) float;

__device__ __forceinline__ float b2f(short s) {
    return __uint_as_float(((unsigned int)(unsigned short)s) << 16);
}
__device__ __forceinline__ short f2b(float f) {
    unsigned int u = __float_as_uint(f);
    u += 0x7fffu + ((u >> 16) & 1u);   // round-to-nearest-even
    return (short)(u >> 16);
}
__device__ __forceinline__ f32x4 mfma16(bf16x8 a, bf16x8 b, f32x4 c) {
    return __builtin_amdgcn_mfma_f32_16x16x32_bf16(a, b, c, 0, 0, 0);
}
// args are always <= 0 here (online-softmax differences); __expf -> v_exp_f32
__device__ __forceinline__ float safe_exp(float x) {
    return __expf((x <= 0.f) ? x : 0.f);
}
// gelu(v) = 0.5 v (1 + erf(v/sqrt2)); erf via A&S 7.1.25 (|err| <= 2.5e-5,
// branch-free: rcp + exp + 5 fma). 100x below bf16 output quantization.
__device__ __forceinline__ float fast_gelu(float v) {
    float z  = fabsf(v) * 0.70710678118f;
    float t  = __builtin_amdgcn_rcpf(fmaf(0.47047f, z, 1.f));
    float e  = __expf(-z * z);
    float p  = t * fmaf(t, fmaf(t, 0.7478556f, -0.0958798f), 0.3480242f);
    float er = fmaf(-p, e, 1.f);                  // erf(|z|)
    er = (v < 0.f) ? -er : er;
    return 0.5f * v * (1.f + er);
}
// async global->LDS, 16 B per lane; LDS dest = wave-uniform base + lane*16
__device__ __forceinline__ void load_lds16(const short* g, short* l) {
    __builtin_amdgcn_global_load_lds((const __attribute__((address_space(1))) void*)g,
                                     (__attribute__((address_space(3))) void*)l, 16, 0, 0);
}
// raw barrier: LDS ops drained for visibility; in-flight GLOBAL loads are
// NOT drained (unlike __syncthreads' vmcnt(0)) — the async-staging enabler.
__device__ __forceinline__ void barrier_lds_only() {
    asm volatile("s_waitcnt lgkmcnt(0)" ::: "memory");
    __builtin_amdgcn_s_barrier();
    asm volatile("" ::: "memory");
}
#define NEGF (-3.0e38f)

// ---------------------------------------------------------------------------
// prep_all — fused preprocessing, one dispatch, 256 thr:
//   blocks [0,3072)      : wq/wk/wv fp32 -> bf16 transpose (32x32 tiles)
//   blocks [3072,7168)   : w1 (1024x4096) -> W1T
//   blocks [7168,11264)  : w2 (4096x1024) -> W2T
//   blocks [11264,15360) : x fp32 -> bf16 (1024 elems/block)
// ---------------------------------------------------------------------------
__global__ __launch_bounds__(256) void prep_all(
    const float* __restrict__ wq, const float* __restrict__ wk,
    const float* __restrict__ wv, const float* __restrict__ w1,
    const float* __restrict__ w2, const float* __restrict__ x,
    short* __restrict__ wqkvt, short* __restrict__ w1t,
    short* __restrict__ w2t, short* __restrict__ xb)
{
    __shared__ short tile[32][33];
    int id = blockIdx.x;
    int t = threadIdx.x;
    int tx = t & 31, ty = t >> 5;
    if (id < 3072) {
        int z = id >> 10, rem = id & 1023;
        int bx = (rem & 31) * 32, by = (rem >> 5) * 32;
        const float* in = (z == 0) ? wq : (z == 1) ? wk : wv;
        short* dst = wqkvt + (size_t)z * 1048576;
        for (int i = ty; i < 32; i += 8)
            tile[i][tx] = f2b(in[(size_t)(by + i) * 1024 + bx + tx]);
        __syncthreads();
        for (int i = ty; i < 32; i += 8)
            dst[(size_t)(bx + i) * 1024 + by + tx] = tile[tx][i];
    } else if (id < 7168) {
        int rem = id - 3072;                       // w1: R=1024, C=4096
        int bx = (rem & 127) * 32, by = (rem >> 7) * 32;
        for (int i = ty; i < 32; i += 8)
            tile[i][tx] = f2b(w1[(size_t)(by + i) * 4096 + bx + tx]);
        __syncthreads();
        for (int i = ty; i < 32; i += 8)
            w1t[(size_t)(bx + i) * 1024 + by + tx] = tile[tx][i];
    } else if (id < 11264) {
        int rem = id - 7168;                       // w2: R=4096, C=1024
        int bx = (rem & 31) * 32, by = (rem >> 5) * 32;
        for (int i = ty; i < 32; i += 8)
            tile[i][tx] = f2b(w2[(size_t)(by + i) * 1024 + bx + tx]);
        __syncthreads();
        for (int i = ty; i < 32; i += 8)
            w2t[(size_t)(bx + i) * 4096 + by + tx] = tile[tx][i];
    } else {
        int rem = id - 11264;
        int i = (rem * 256 + t) * 4;
        f32x4 v = *(const f32x4*)(x + i);
        bf16x4 o;
#pragma unroll
        for (int j = 0; j < 4; ++j) o[j] = f2b(v[j]);
        *(bf16x4*)(xb + i) = o;
    }
}

// ---------------------------------------------------------------------------
// GEMM 128x128, BK=64, XOR-swizzled LDS k-chunks. NATURAL block order.
// mode 0: QKV — bias by col segment, Q scaled, V staged+transposed -> Vt
// mode 1: C = bf16(gelu(acc + bias0[col]))
// Epilogue always stages the tile in LDS, then coalesced 16-B stores.
// ---------------------------------------------------------------------------
__global__ __launch_bounds__(256, 4) void gemm_bt(
    const short* __restrict__ A, const short* __restrict__ Bt,
    const float* __restrict__ bias0, const float* __restrict__ bias1,
    const float* __restrict__ bias2,
    short* __restrict__ C, short* __restrict__ Vt,
    int M, int N, int K, float scale, int mode)
{
    __shared__ short sh[128 * 136];   // 34.8 KB; main loop uses first 16K shorts
    short* As = sh;
    short* Bs = sh + 8192;
    int m0 = blockIdx.x * 128, n0 = blockIdx.y * 128;
    int t = threadIdx.x;
    int wave = t >> 6, lane = t & 63, quad = lane >> 4, l16 = lane & 15;
    int wr = (wave >> 1) * 64, wc = (wave & 1) * 64;

    // staging pointers: 4 chunks per wave per buffer
    const short* ap[4]; const short* bp[4]; short* la[4]; short* lb[4];
    int gk = (((lane & 7) ^ (lane >> 3)) * 8);
#pragma unroll
    for (int l = 0; l < 4; ++l) {
        int c = wave * 4 + l;
        int row = c * 8 + (lane >> 3);
        ap[l] = A  + (size_t)(m0 + row) * K + gk;
        bp[l] = Bt + (size_t)(n0 + row) * K + gk;
        la[l] = As + c * 512;
        lb[l] = Bs + c * 512;
    }
    int sw = l16 & 7;   // frag-read swizzle key

    f32x4 acc[4][4] = {};
    for (int k0 = 0; k0 < K; k0 += 64) {
#pragma unroll
        for (int l = 0; l < 4; ++l) { load_lds16(ap[l] + k0, la[l]); load_lds16(bp[l] + k0, lb[l]); }
        __syncthreads();
#pragma unroll
        for (int ks = 0; ks < 2; ++ks) {
            int slot = ((ks * 4 + quad) ^ sw) * 8;
            bf16x8 af[4], bfr[4];
#pragma unroll
            for (int i = 0; i < 4; ++i)
                af[i] = *(bf16x8*)(As + (wr + i * 16 + l16) * 64 + slot);
#pragma unroll
            for (int j = 0; j < 4; ++j)
                bfr[j] = *(bf16x8*)(Bs + (wc + j * 16 + l16) * 64 + slot);
#pragma unroll
            for (int i = 0; i < 4; ++i)
#pragma unroll
                for (int j = 0; j < 4; ++j)
                    acc[i][j] = mfma16(af[i], bfr[j], acc[i][j]);
        }
        __syncthreads();
    }
    // after final barrier, all LDS reads are done -> sh reusable for staging

    int seg0 = n0 >> 10;   // tiles are 128-aligned: never straddle a segment
    if (mode == 1 || seg0 < 2) {
        // ---- stage bf16 tile in LDS: sh[row*136 + col], row/col in [0,128)
        if (mode == 1) {
#pragma unroll
            for (int j = 0; j < 4; ++j) {
                int col = n0 + wc + j * 16 + l16;
                float bs = bias0[col];
#pragma unroll
                for (int i = 0; i < 4; ++i)
#pragma unroll
                    for (int r = 0; r < 4; ++r) {
                        float v = fast_gelu(acc[i][j][r] + bs);
                        sh[(wr + i * 16 + quad * 4 + r) * 136 + wc + j * 16 + l16] = f2b(v);
                    }
            }
        } else {
            float sc = (seg0 == 0) ? scale : 1.0f;
            const float* bpt = (seg0 == 0) ? bias0 : bias1;
#pragma unroll
            for (int j = 0; j < 4; ++j) {
                int col = n0 + wc + j * 16 + l16;
                float bs = bpt[col & 1023];
#pragma unroll
                for (int i = 0; i < 4; ++i)
#pragma unroll
                    for (int r = 0; r < 4; ++r)
                        sh[(wr + i * 16 + quad * 4 + r) * 136 + wc + j * 16 + l16] =
                            f2b((acc[i][j][r] + bs) * sc);
            }
        }
        __syncthreads();
        // ---- coalesced write-out: 2 threads per row, 8 x 16 B each
        int row = t >> 1, half = t & 1;
        const short* src = sh + row * 136 + half * 64;
        short* dst = C + (size_t)(m0 + row) * N + n0 + half * 64;
#pragma unroll
        for (int cgk = 0; cgk < 8; ++cgk)
            *(bf16x8*)(dst + cgk * 8) = *(const bf16x8*)(src + cgk * 8);
    } else {
        // ---- V part: stage TRANSPOSED in LDS (sh[c*136 + row]), then write
        //      Vt (b, h, d, s) with 16-B chunks coalesced along s.
#pragma unroll
        for (int j = 0; j < 4; ++j) {
            int cl = wc + j * 16 + l16;                 // local col in [0,128)
            float bs = bias2[(n0 & 1023) + cl];
#pragma unroll
            for (int i = 0; i < 4; ++i)
#pragma unroll
                for (int r = 0; r < 4; ++r)
                    sh[cl * 136 + wr + i * 16 + quad * 4 + r] = f2b(acc[i][j][r] + bs);
        }
        __syncthreads();
        int h0 = (n0 & 1023) >> 6;                      // first head of tile
        int bb = m0 >> 11, s0 = m0 & 2047;
        int sc = t & 15;                                // s-chunk within tile
#pragma unroll
        for (int cgk = 0; cgk < 8; ++cgk) {
            int cl = (t >> 4) + cgk * 16;               // local col
            int h = h0 + (cl >> 6), d = cl & 63;
            *(bf16x8*)(Vt + (((size_t)(bb * 16 + h)) * 64 + d) * 2048 + s0 + sc * 8) =
                *(const bf16x8*)(sh + cl * 136 + sc * 8);
        }
    }
}

// ---------------------------------------------------------------------------
// MLP2 GEMM: 64x64 block tile, BK=64, TWO waves (128 thr), wave owns 32x64
// (acc[2][4]) -> 21.8 FLOP/LDS-byte. Double-buffered, counted vmcnt(8)
// (8 loads/thread/tile stay in flight). Natural block order. grid
// (M/64, N/64) = 1024 -> 4 blocks/CU (8 waves/CU), 32 KB LDS.
// Cf = A@B + bias + resf (fp32 out).
// ---------------------------------------------------------------------------
__global__ __launch_bounds__(128, 2) void gemm64w2_db(
    const short* __restrict__ A, const short* __restrict__ Bt,
    const float* __restrict__ bias, const float* __restrict__ resf,
    float* __restrict__ Cf, int M, int N, int K)
{
    __shared__ short As[2][64 * 64];
    __shared__ short Bs[2][64 * 64];
    int m0 = blockIdx.x * 64, n0 = blockIdx.y * 64;
    int t = threadIdx.x;                 // 0..127
    int wave = t >> 6, lane = t & 63, quad = lane >> 4, l16 = lane & 15;
    int wr = wave * 32;

    const short* ap[4]; const short* bp[4]; int lo[4];
    int gk = (((lane & 7) ^ (lane >> 3)) * 8);
#pragma unroll
    for (int l = 0; l < 4; ++l) {
        int c = wave * 4 + l;            // chunks 0..7 across the 2 waves
        int row = c * 8 + (lane >> 3);
        ap[l] = A  + (size_t)(m0 + row) * K + gk;
        bp[l] = Bt + (size_t)(n0 + row) * K + gk;
        lo[l] = c * 512;
    }
    int sw = l16 & 7;

    const int nt = K >> 6;
#pragma unroll
    for (int l = 0; l < 4; ++l) { load_lds16(ap[l], &As[0][lo[l]]); load_lds16(bp[l], &Bs[0][lo[l]]); }

    f32x4 acc[2][4] = {};
    for (int ti = 0; ti < nt; ++ti) {
        int cur = ti & 1;
        if (ti + 1 < nt) {
            int k0 = (ti + 1) << 6;
#pragma unroll
            for (int l = 0; l < 4; ++l) {
                load_lds16(ap[l] + k0, &As[cur ^ 1][lo[l]]);
                load_lds16(bp[l] + k0, &Bs[cur ^ 1][lo[l]]);
            }
            asm volatile("s_waitcnt vmcnt(8)" ::: "memory");  // cur's 8 done
        } else {
            asm volatile("s_waitcnt vmcnt(0)" ::: "memory");
        }
        __builtin_amdgcn_s_barrier();
        asm volatile("" ::: "memory");

        const short* as = &As[cur][0];
        const short* bs = &Bs[cur][0];
#pragma unroll
        for (int ks = 0; ks < 2; ++ks) {
            int slot = ((ks * 4 + quad) ^ sw) * 8;
            bf16x8 af[2], bfr[4];
#pragma unroll
            for (int i = 0; i < 2; ++i)
                af[i] = *(bf16x8*)(as + (wr + i * 16 + l16) * 64 + slot);
#pragma unroll
            for (int j = 0; j < 4; ++j)
                bfr[j] = *(bf16x8*)(bs + (j * 16 + l16) * 64 + slot);
#pragma unroll
            for (int i = 0; i < 2; ++i)
#pragma unroll
                for (int j = 0; j < 4; ++j)
                    acc[i][j] = mfma16(af[i], bfr[j], acc[i][j]);
        }
        asm volatile("" ::: "memory");
        __builtin_amdgcn_s_barrier();   // protect buf cur^1 before next stage
    }

#pragma unroll
    for (int j = 0; j < 4; ++j) {
        int col = n0 + j * 16 + l16;
        float bs = bias[col];
#pragma unroll
        for (int i = 0; i < 2; ++i) {
#pragma unroll
            for (int r = 0; r < 4; ++r) {
                int row = m0 + wr + i * 16 + quad * 4 + r;
                Cf[(size_t)row * N + col] = acc[i][j][r] + bs + resf[(size_t)row * N + col];
            }
        }
    }
}

// ---------------------------------------------------------------------------
// Windowed attention with global column. q-chunk 64, K/V staged by
// global_load_lds into linear LDS (K [128][64], V [64][128]) with the
// pre-swizzled-global-source XOR pattern; counted vmcnt(4) keeps one tile's
// loads in flight across barriers (K lands under PV, V under QK^T+softmax).
// No reg staging -> no spills. LDS 50688 B -> 3 blocks/CU.
// Boundary tiles: load rows/cols clamped; jcol outside [0,2048) masked to
// NEGF (=> P=0, garbage K/V contributes nothing).
// smem: P/Q 17408 (Q 64x72, P 64x136) | K 16384 | V 16384 | gkf/gvf 512
// ---------------------------------------------------------------------------
__global__ __launch_bounds__(256, 3) void attn_kernel(
    const short* __restrict__ QKV, const short* __restrict__ Vt,
    const int* __restrict__ mask,
    const float* __restrict__ bk, const float* __restrict__ bv,
    short* __restrict__ attn)
{
    extern __shared__ char smem[];
    short* PsQ = (short*)smem;               // Q [64][72] then P [64][136]
    short* Ks  = (short*)(smem + 17408);     // K  [128][64] swizzled chunks
    short* Vs  = (short*)(smem + 33792);     // V  [64][128] swizzled chunks
    float* gkf = (float*)(smem + 50176);
    float* gvf = (float*)(smem + 50432);

    int blk = blockIdx.x;
    int c = blk & 31, h = (blk >> 5) & 15, b = blk >> 9;
    int t = threadIdx.x;
    int wave = t >> 6, lane = t & 63, quad = lane >> 4, l16 = lane & 15;
    int q0 = c * 64;
    const int bs_off = b * 2048;
    const short* Q = QKV + h * 64;
    const short* K = QKV + 1024 + h * 64;
    const short* Vg = Vt + (size_t)(b * 16 + h) * 64 * 2048;
    int sw = l16 & 7;
    int wub = (t & 192) * 8;                 // wave-uniform LDS chunk base

    // Q stage: 64 rows x 64 cols (72-stride, scalar-read later -> pad ok)
#pragma unroll
    for (int l = 0; l < 2; ++l) {
        int idx = l * 256 + t;
        int p = idx >> 3, dc = (idx & 7) * 8;
        *(bf16x8*)(PsQ + p * 72 + dc) =
            *(const bf16x8*)(Q + ((size_t)(bs_off + q0 + p)) * 3072 + dc);
    }
    if (t < 64) { gkf[t] = bk[h * 64 + t]; gvf[t] = bv[h * 64 + t]; }
    __syncthreads();

    bf16x8 aq[2];
#pragma unroll
    for (int ks = 0; ks < 2; ++ks)
        aq[ks] = *(bf16x8*)(PsQ + (wave * 16 + l16) * 72 + ks * 32 + quad * 8);

    float s_g[4];
#pragma unroll
    for (int r = 0; r < 4; ++r) {
        int row = wave * 16 + quad * 4 + r;
        float part = 0.f;
#pragma unroll
        for (int dd = 0; dd < 4; ++dd) {
            int d = l16 * 4 + dd;
            part += b2f(PsQ[row * 72 + d]) * gkf[d];
        }
#pragma unroll
        for (int dsh = 1; dsh < 16; dsh <<= 1) part += __shfl_xor(part, dsh);
        s_g[r] = part;
    }

    f32x4 o_acc[4] = {};
    float m_run[4], l_run[4];
#pragma unroll
    for (int r = 0; r < 4; ++r) { m_run[r] = NEGF; l_run[r] = 0.f; }

    int kt_beg = (q0 == 0) ? 1 : 0;
    int kt_end = (q0 + 128 < 2048) ? 3 : 2;

    // staging issuers: linear LDS dest (wave-uniform base + lane*16),
    // per-lane global source with pre-swizzled chunk (read undoes the XOR)
#define ISSUE_K(JB)                                                          \
    {                                                                        \
        _Pragma("unroll")                                                    \
        for (int l = 0; l < 4; ++l) {                                        \
            int row = l * 32 + (t >> 3);                                     \
            int rg = (JB) + row;                                             \
            rg = (rg < 0) ? 0 : ((rg > 2047) ? 2047 : rg);                   \
            load_lds16(K + (size_t)(bs_off + rg) * 3072 +                    \
                           (((t & 7) ^ (row & 7)) * 8),                      \
                       Ks + l * 2048 + wub);                                 \
        }                                                                    \
    }
#define ISSUE_V(JB)                                                          \
    {                                                                        \
        _Pragma("unroll")                                                    \
        for (int l = 0; l < 4; ++l) {                                        \
            int d = l * 16 + (t >> 4);                                       \
            int sg = (JB) + (((t & 15) ^ (d & 7)) * 8);                      \
            sg = (sg < 0) ? 0 : ((sg > 2040) ? 2040 : sg);                   \
            load_lds16(Vg + (size_t)d * 2048 + sg,                           \
                       Vs + l * 2048 + wub);                                 \
        }                                                                    \
    }

    // prologue: issue K[beg] then V[beg]  (outstanding: K 4, V 4 per thread)
    {
        int jb0 = q0 + (kt_beg - 1) * 128;
        ISSUE_K(jb0);
        ISSUE_V(jb0);
    }

    for (int kt = kt_beg; kt < kt_end; ++kt) {
        int jb = q0 + (kt - 1) * 128;
        // K[kt] landed (4 V loads may remain in flight)
        asm volatile("s_waitcnt vmcnt(4)" ::: "memory");
        __builtin_amdgcn_s_barrier();
        asm volatile("" ::: "memory");

        f32x4 s_acc[8] = {};
#pragma unroll
        for (int ks = 0; ks < 2; ++ks) {
            int slot = ((ks * 4 + quad) ^ sw) * 8;
            bf16x8 bk8[8];
#pragma unroll
            for (int tj = 0; tj < 8; ++tj)
                bk8[tj] = *(bf16x8*)(Ks + (tj * 16 + l16) * 64 + slot);
#pragma unroll
            for (int tj = 0; tj < 8; ++tj)
                s_acc[tj] = mfma16(aq[ks], bk8[tj], s_acc[tj]);
        }

        float negj[8]; int jcol[8];
#pragma unroll
        for (int tj = 0; tj < 8; ++tj) {
            jcol[tj] = jb + tj * 16 + l16;
            bool jv = (jcol[tj] >= 0) && (jcol[tj] < 2048);
            int jc = jv ? jcol[tj] : 0;
            negj[tj] = (!jv || (mask[bs_off + jc] != 0)) ? NEGF : 0.f;
        }
        float tmax[4];
#pragma unroll
        for (int r = 0; r < 4; ++r) tmax[r] = NEGF;
        int irow_base = q0 + wave * 16 + quad * 4;
#pragma unroll
        for (int tj = 0; tj < 8; ++tj)
#pragma unroll
            for (int r = 0; r < 4; ++r) {
                int dj = jcol[tj] - (irow_base + r);
                float sc = (dj >= -128 && dj <= 128) ? (s_acc[tj][r] + negj[tj]) : NEGF;
                s_acc[tj][r] = sc;
                tmax[r] = fmaxf(tmax[r], sc);
            }
#pragma unroll
        for (int r = 0; r < 4; ++r)
#pragma unroll
            for (int dsh = 1; dsh < 16; dsh <<= 1)
                tmax[r] = fmaxf(tmax[r], __shfl_xor(tmax[r], dsh));

        float alpha[4], lsum[4];
#pragma unroll
        for (int r = 0; r < 4; ++r) {
            float mnew = fmaxf(m_run[r], tmax[r]);
            alpha[r] = safe_exp(m_run[r] - mnew);
            m_run[r] = mnew;
            lsum[r] = 0.f;
        }
#pragma unroll
        for (int tj = 0; tj < 8; ++tj)
#pragma unroll
            for (int r = 0; r < 4; ++r) {
                float p = safe_exp(s_acc[tj][r] - m_run[r]);
                lsum[r] += p;
                PsQ[(wave * 16 + quad * 4 + r) * 136 + tj * 16 + l16] = f2b(p);
            }
#pragma unroll
        for (int r = 0; r < 4; ++r) {
#pragma unroll
            for (int dsh = 1; dsh < 16; dsh <<= 1) lsum[r] += __shfl_xor(lsum[r], dsh);
            l_run[r] = l_run[r] * alpha[r] + lsum[r];
        }
#pragma unroll
        for (int dj = 0; dj < 4; ++dj)
#pragma unroll
            for (int r = 0; r < 4; ++r) o_acc[dj][r] *= alpha[r];

        barrier_lds_only();   // all waves done reading Ks; P visible

        // K region free: issue next K (lands during PV)
        if (kt + 1 < kt_end) {
            ISSUE_K(jb + 128);
            asm volatile("s_waitcnt vmcnt(4)" ::: "memory");  // V[kt] landed
        } else {
            asm volatile("s_waitcnt vmcnt(0)" ::: "memory");
        }
        __builtin_amdgcn_s_barrier();
        asm volatile("" ::: "memory");

#pragma unroll
        for (int ks = 0; ks < 4; ++ks) {
            int slot = ((ks * 4 + quad) ^ sw) * 8;
            bf16x8 ap = *(bf16x8*)(PsQ + (wave * 16 + l16) * 136 + ks * 32 + quad * 8);
            bf16x8 bv8[4];
#pragma unroll
            for (int dj = 0; dj < 4; ++dj)
                bv8[dj] = *(bf16x8*)(Vs + (dj * 16 + l16) * 128 + slot);
#pragma unroll
            for (int dj = 0; dj < 4; ++dj)
                o_acc[dj] = mfma16(ap, bv8[dj], o_acc[dj]);
        }
        barrier_lds_only();   // all waves done reading Vs

        // V region free: issue next V (lands during next QK^T + softmax)
        if (kt + 1 < kt_end) ISSUE_V(jb + 128);
    }

    int irow_base = q0 + wave * 16 + quad * 4;
#pragma unroll
    for (int r = 0; r < 4; ++r) {
        int i = irow_base + r;
        float m2 = fmaxf(m_run[r], s_g[r]);
        float pg = safe_exp(s_g[r] - m2);
        float al = safe_exp(m_run[r] - m2);
        float l2 = l_run[r] * al + pg;
        float invl = 1.f / fmaxf(l2, 1e-30f);
        float qm = (mask[bs_off + i] > 0) ? 0.f : 1.f;
#pragma unroll
        for (int dj = 0; dj < 4; ++dj) {
            int d = dj * 16 + l16;
            float val = (o_acc[dj][r] * al + pg * gvf[d]) * invl * qm;
            attn[((size_t)(bs_off + i)) * 1024 + h * 64 + d] = f2b(val);
        }
    }
#undef ISSUE_K
#undef ISSUE_V
}

// ---------------------------------------------------------------------------
// y = LN(x + attn) * g + b ; writes bf16 (GEMM input) AND fp32 (residual).
// ---------------------------------------------------------------------------
__global__ __launch_bounds__(256) void resid_ln(
    const float* __restrict__ x, const short* __restrict__ attn,
    const float* __restrict__ g, const float* __restrict__ be,
    short* __restrict__ yb, float* __restrict__ yf)
{
    int row = blockIdx.x, t = threadIdx.x;
    int lane = t & 63, wave = t >> 6;
    const size_t base = (size_t)row * 1024;
    float v[4]; float s = 0.f, s2 = 0.f;
#pragma unroll
    for (int i = 0; i < 4; ++i) {
        int c = i * 256 + t;
        float val = x[base + c] + b2f(attn[base + c]);
        v[i] = val; s += val; s2 += val * val;
    }
#pragma unroll
    for (int off = 32; off > 0; off >>= 1) { s += __shfl_xor(s, off); s2 += __shfl_xor(s2, off); }
    __shared__ float red[8];
    if (lane == 0) { red[wave] = s; red[4 + wave] = s2; }
    __syncthreads();
    s  = red[0] + red[1] + red[2] + red[3];
    s2 = red[4] + red[5] + red[6] + red[7];
    float mu  = s * (1.f / 1024.f);
    float var = s2 * (1.f / 1024.f) - mu * mu;
    float inv = rsqrtf(fmaxf(var, 0.f) + 1e-5f);
#pragma unroll
    for (int i = 0; i < 4; ++i) {
        int c = i * 256 + t;
        float o = (v[i] - mu) * inv * g[c] + be[c];
        yb[base + c] = f2b(o);
        yf[base + c] = o;
    }
}

// ---------------------------------------------------------------------------
// workspace layout, units = bf16 elements (2 B). total 47M units = 94 MB.
// ---------------------------------------------------------------------------
static constexpr size_t MEG      = 1048576;
static constexpr size_t OFF_WQKV = 0;            // 3M  (3072x1024 bf16)
static constexpr size_t OFF_W1T  = 3 * MEG;      // 4M
static constexpr size_t OFF_W2T  = 7 * MEG;      // 4M
static constexpr size_t OFF_XB   = 11 * MEG;     // 4M
static constexpr size_t OFF_QKV  = 15 * MEG;     // 12M (4096x3072 bf16; V third unused)
static constexpr size_t OFF_VT   = 27 * MEG;     // 4M
static constexpr size_t OFF_ATT  = 31 * MEG;     // 4M
static constexpr size_t OFF_YN   = 35 * MEG;     // 4M (bf16)
static constexpr size_t OFF_YF   = 39 * MEG;     // 8M units = 4M fp32
static constexpr size_t OFF_H    = OFF_QKV;      // 16M, aliases QKV+VT (dead)

extern "C" void kernel_launch(void* const* d_in, const int* in_sizes, int n_in,
                              void* d_out, int out_size, void* d_ws, size_t ws_size,
                              hipStream_t stream) {
    (void)in_sizes; (void)n_in; (void)out_size; (void)ws_size;
    const float* x    = (const float*)d_in[0];
    const int*   mask = (const int*)  d_in[1];
    const float* wq   = (const float*)d_in[2];
    const float* bq   = (const float*)d_in[3];
    const float* wk   = (const float*)d_in[4];
    const float* bk   = (const float*)d_in[5];
    const float* wv   = (const float*)d_in[6];
    const float* bv   = (const float*)d_in[7];
    // d_in[8..13] (global-query branch) are provably dead for the output
    const float* lng  = (const float*)d_in[14];
    const float* lnb  = (const float*)d_in[15];
    const float* w1   = (const float*)d_in[16];
    const float* b1   = (const float*)d_in[17];
    const float* w2   = (const float*)d_in[18];
    const float* b2   = (const float*)d_in[19];
    short* ws  = (short*)d_ws;
    float* out = (float*)d_out;

    // all preprocessing in ONE dispatch (launch-overhead cut: 9 -> 6 kernels)
    prep_all<<<15360, 256, 0, stream>>>(wq, wk, wv, w1, w2, x,
                                        ws + OFF_WQKV, ws + OFF_W1T,
                                        ws + OFF_W2T, ws + OFF_XB);

    // QKV = x @ [wq|wk|wv] + [bq|bk|bv]; Q scaled 1/8; V staged -> Vt fused
    gemm_bt<<<dim3(32, 24), 256, 0, stream>>>(ws + OFF_XB, ws + OFF_WQKV,
                                              bq, bk, bv,
                                              ws + OFF_QKV, ws + OFF_VT,
                                              4096, 3072, 1024, 0.125f, 0);

    // q-chunk 64: grid 32 chunks x 16 heads x 2 batches = 1024 blocks
    attn_kernel<<<1024, 256, 50688, stream>>>(ws + OFF_QKV, ws + OFF_VT,
                                              mask, bk, bv, ws + OFF_ATT);

    resid_ln<<<4096, 256, 0, stream>>>(x, ws + OFF_ATT, lng, lnb,
                                       ws + OFF_YN, (float*)(ws + OFF_YF));

    // h = gelu(y@w1 + b1)
    gemm_bt<<<dim3(32, 32), 256, 0, stream>>>(ws + OFF_YN, ws + OFF_W1T,
                                              b1, nullptr, nullptr,
                                              ws + OFF_H, nullptr,
                                              4096, 4096, 1024, 1.0f, 1);
    // out = y + h@w2 + b2 (64x64 block, 2 waves of 32x64, dbuf + vmcnt(8))
    gemm64w2_db<<<dim3(64, 16), 128, 0, stream>>>(ws + OFF_H, ws + OFF_W2T,
                                                  b2, (const float*)(ws + OFF_YF),
                                                  out, 4096, 1024, 4096);
}